// Round 4
// baseline (871.989 us; speedup 1.0000x reference)
//
#include <hip/hip_runtime.h>
#include <stdint.h>

#define NB 16
#define TQ 1369
#define TS 5476
#define DD 768

#define BM 128
#define BN 128
#define KB 24          // k-blocks of 32 (768/32)
#define RBQ 11         // query row-blocks per n  (11*128 = 1408)
#define RBS 43         // support row-blocks per n (43*128 = 5504)
#define QPAD 1408
#define SPAD 5504
#define NROWS (NB * QPAD)        // 22528 padded query rows total
#define CAP 8                    // candidate slots per (row, tile) record
#define EPS_SEL 2.5e-3f

typedef float f32x4 __attribute__((ext_vector_type(4)));
typedef short short8 __attribute__((ext_vector_type(8)));
typedef unsigned short ushort;
typedef unsigned long long ull;

// ---------- helpers ----------

__device__ inline float waveReduceSum(float v) {
    #pragma unroll
    for (int m = 32; m >= 1; m >>= 1) v += __shfl_xor(v, m);
    return v;
}

// fp32 -> bf16 with round-to-nearest-even, returns low 16 bits
__device__ inline unsigned bf16rne(float x) {
    unsigned u = __float_as_uint(x);
    return (u + 0x7FFFu + ((u >> 16) & 1u)) >> 16;
}
__device__ inline unsigned pack2(float lo, float hi) {
    return bf16rne(lo) | (bf16rne(hi) << 16);
}

__device__ inline f32x4 mfma16(short8 a, short8 b, f32x4 c) {
    return __builtin_amdgcn_mfma_f32_16x16x32_bf16(a, b, c, 0, 0, 0);
}

// async 16B/lane global->LDS DMA (wave-uniform LDS base + lane*16)
__device__ inline void async16(const void* g, void* l) {
    __builtin_amdgcn_global_load_lds(
        (const __attribute__((address_space(1))) unsigned*)g,
        (__attribute__((address_space(3))) unsigned*)l, 16, 0, 0);
}

// monotone float<->uint mapping so unsigned max == float max
__device__ inline unsigned fsort(float f) {
    unsigned u = __float_as_uint(f);
    return (u & 0x80000000u) ? ~u : (u | 0x80000000u);
}
__device__ inline float funsort(unsigned u) {
    return __uint_as_float((u & 0x80000000u) ? (u & 0x7FFFFFFFu) : ~u);
}

// ---------- kernel 1: cls = l2norm(mean over shots) ----------

__global__ __launch_bounds__(256) void cls_kernel(const float* __restrict__ xc,
                                                  float* __restrict__ cls) {
    int n = blockIdx.x, tid = threadIdx.x;
    const float* base = xc + (size_t)n * 4 * DD;
    float v[3]; float ss = 0.f;
    #pragma unroll
    for (int i = 0; i < 3; i++) {
        int e = tid + i * 256;
        float a = base[e] + base[DD + e] + base[2 * DD + e] + base[3 * DD + e];
        v[i] = a * 0.25f; ss += v[i] * v[i];
    }
    ss = waveReduceSum(ss);
    __shared__ float red[4]; __shared__ float rn;
    if ((tid & 63) == 0) red[tid >> 6] = ss;
    __syncthreads();
    if (tid == 0) {
        float t = red[0] + red[1] + red[2] + red[3];
        rn = 1.0f / fmaxf(sqrtf(t), 1e-12f);
    }
    __syncthreads();
    float r = rn;
    #pragma unroll
    for (int i = 0; i < 3; i++) cls[(size_t)n * DD + tid + i * 256] = v[i] * r;
}

// ---------- kernel 2a: norms only (wave per real row, fully coalesced reads) ----------

__global__ __launch_bounds__(256) void norm_kernel(const float* __restrict__ Q,
                                                   const float* __restrict__ S,
                                                   float* __restrict__ rq,
                                                   float* __restrict__ rs) {
    int wid = (int)(blockIdx.x * 4u + (threadIdx.x >> 6));   // 109,520 waves exactly
    int lane = threadIdx.x & 63;
    bool isQ = wid < NB * TQ;
    const float* src;
    float* dst;
    if (isQ) { src = Q + (size_t)wid * DD; dst = rq + wid; }
    else     { int w2 = wid - NB * TQ; src = S + (size_t)w2 * DD; dst = rs + w2; }
    float ss = 0.f;
    #pragma unroll
    for (int i = 0; i < 3; i++) {
        float4 x = ((const float4*)src)[lane + i * 64];
        ss += x.x * x.x + x.y * x.y + x.z * x.z + x.w * x.w;
    }
    ss = waveReduceSum(ss);
    if (lane == 0) *dst = 1.0f / fmaxf(sqrtf(ss), 1e-12f);
}

// ---------- kernel 2b: pack normalized bf16 tiles, coalesced both sides ----------
// grid (KB, RBQ+RBS, NB). Block = one (row-block, kb) slab: 128 rows x 32 cols.
// Thread (p = tid&127, half = tid>>7): reads ONE full 64B line of row p
// (16 floats at col kb*32 + half*16), scales, packs, writes two 16B chunks that
// are contiguous across the 128 p-threads (4 x 2KB streams per block).
// Output layout identical to old split: addr = kb*4096 + g*1024 + p*8 + e,
// g = (col>>3)&3, e = col&7  (col>>5 == kb within this block).

__global__ __launch_bounds__(256) void pack_kernel(const float* __restrict__ Q,
                                                   const float* __restrict__ S,
                                                   const float* __restrict__ rq,
                                                   const float* __restrict__ rs,
                                                   ushort* __restrict__ Qh,
                                                   ushort* __restrict__ Sh) {
    int kb = blockIdx.x, by = blockIdx.y, n = blockIdx.z;
    bool isQ = by < RBQ;
    int rb = isQ ? by : by - RBQ;
    int p = threadIdx.x & 127, half = threadIdx.x >> 7;
    int row = rb * 128 + p;
    int nreal = isQ ? TQ : TS;
    ushort* outp = (isQ ? Qh + (size_t)(n * RBQ + rb) * KB * 4096
                        : Sh + (size_t)(n * RBS + rb) * KB * 4096) + (size_t)kb * 4096;
    int g0 = half * 2;

    if (row >= nreal) {                 // zero pad rows (ws is poisoned 0xAA)
        uint4 z = {0u, 0u, 0u, 0u};
        *(uint4*)(outp + g0 * 1024 + p * 8)       = z;
        *(uint4*)(outp + (g0 + 1) * 1024 + p * 8) = z;
        return;
    }

    const float4* src = (const float4*)((isQ ? Q + ((size_t)n * TQ + row) * DD
                                             : S + ((size_t)n * TS + row) * DD)
                                        + kb * 32 + half * 16);
    float r = isQ ? rq[n * TQ + row] : rs[n * TS + row];
    float4 a = src[0], b = src[1], c = src[2], d = src[3];

    uint4 o1, o2;
    o1.x = pack2(a.x * r, a.y * r); o1.y = pack2(a.z * r, a.w * r);
    o1.z = pack2(b.x * r, b.y * r); o1.w = pack2(b.z * r, b.w * r);
    o2.x = pack2(c.x * r, c.y * r); o2.y = pack2(c.z * r, c.w * r);
    o2.z = pack2(d.x * r, d.y * r); o2.w = pack2(d.z * r, d.w * r);

    *(uint4*)(outp + g0 * 1024 + p * 8)       = o1;   // cols lc=half*16+0..7  (g=g0)
    *(uint4*)(outp + (g0 + 1) * 1024 + p * 8) = o2;   // cols lc=half*16+8..15 (g=g0+1)
}

// ---------- kernel 3: bf16 GEMM tile + per-(row,tile) max/argmax/candidate record ----------
// grid (RBQ, RBS, NB) — one 128x128 tile per block (proven 738 MB fetch via L2/LLC
// sharing among co-resident same-by blocks). Epilogue: per row, tile max + argmax
// (16-lane shfl reduce w/ index), push others >= tilemax - EPS.
// tilemax <= globalmax, so records are a superset of {d >= globalmax - EPS}.
// Record: hdr[by*NROWS + rowg] = (max, cnt); cpair[rec*CAP + 0] = argmax (always).

__global__ __launch_bounds__(256, 4) void gemm_sel(const ushort* __restrict__ Qh,
                                                   const ushort* __restrict__ Sh,
                                                   float2* __restrict__ hdr,
                                                   uint2* __restrict__ cpair) {
    __shared__ __align__(16) ushort As[4096];   // 8 KB
    __shared__ __align__(16) ushort Bs[4096];   // 8 KB
    __shared__ ull key[128];                    // packed (fsort(max)<<32 | 8191-col)
    __shared__ int cnt[128];
    __shared__ uint2 cand[128][CAP];            // slots 1..CAP-1 used (0 = argmax)

    int tid = threadIdx.x, w = tid >> 6, lane = tid & 63;
    int bx = blockIdx.x, by = blockIdx.y, n = blockIdx.z;
    int wm = w & 1, wn = w >> 1, g4 = lane >> 4, c16 = lane & 15;

    if (tid < 128) { key[tid] = 0ull; cnt[tid] = 1; }   // slot 0 reserved for argmax
    __syncthreads();

    // waves 0,1 stage A halves; 2,3 stage B halves
    const char* gsrc = (const char*)((w < 2)
        ? (Qh + (size_t)(n * RBQ + bx) * KB * 4096)
        : (Sh + (size_t)(n * RBS + by) * KB * 4096)) + wm * 4096 + lane * 16;
    char* lbase = (char*)((w < 2) ? As : Bs) + wm * 4096;

    f32x4 acc[4][4] = {};
    int aoff = g4 * 1024 + wm * 512 + c16 * 8;
    int boff = g4 * 1024 + wn * 512 + c16 * 8;

    for (int kb = 0; kb < KB; kb++) {
        #pragma unroll
        for (int j = 0; j < 4; j++)
            async16(gsrc + (size_t)kb * 8192 + j * 1024, lbase + j * 1024);
        __syncthreads();

        short8 ah[4], bh[4];
        #pragma unroll
        for (int i = 0; i < 4; i++) {
            ah[i] = *(const short8*)&As[aoff + i * 128];
            bh[i] = *(const short8*)&Bs[boff + i * 128];
        }
        #pragma unroll
        for (int mi = 0; mi < 4; mi++)
            #pragma unroll
            for (int ni = 0; ni < 4; ni++)
                acc[mi][ni] = mfma16(ah[mi], bh[ni], acc[mi][ni]);
        __syncthreads();
    }

    // ---- epilogue: per-row tile max + argmax ----
    // C layout: row = wm*64 + mi*16 + g4*4 + r, col = by*128 + wn*64 + ni*16 + c16
    int colb = by * 128 + wn * 64 + c16;
    bool edge = (by == RBS - 1);            // only tile containing pad cols

    #pragma unroll
    for (int mi = 0; mi < 4; mi++) {
        #pragma unroll
        for (int r = 0; r < 4; r++) {
            float v = -1e30f; int c = 0;
            #pragma unroll
            for (int ni = 0; ni < 4; ni++) {
                float d = acc[mi][ni][r];
                int col = colb + ni * 16;
                if ((!edge || col < TS) && d > v) { v = d; c = col; }
            }
            #pragma unroll
            for (int m = 1; m < 16; m <<= 1) {   // xor<16 stays within 16-lane group
                float ov = __shfl_xor(v, m);
                int   oc = __shfl_xor(c, m);
                if (ov > v || (ov == v && oc < c)) { v = ov; c = oc; }
            }
            if (c16 == 0) {
                int row = wm * 64 + mi * 16 + g4 * 4 + r;
                ull k = ((ull)fsort(v) << 32) | (unsigned)(8191 - c);
                atomicMax(&key[row], k);
            }
        }
    }
    __syncthreads();

    // ---- push other candidates >= tilemax - EPS ----
    #pragma unroll
    for (int mi = 0; mi < 4; mi++) {
        #pragma unroll
        for (int r = 0; r < 4; r++) {
            int row = wm * 64 + mi * 16 + g4 * 4 + r;
            ull k = key[row];
            float mx = funsort((unsigned)(k >> 32));
            int amc = 8191 - (int)(k & 0xFFFFFFFFull);
            float thr = mx - EPS_SEL;
            #pragma unroll
            for (int ni = 0; ni < 4; ni++) {
                float d = acc[mi][ni][r];
                int col = colb + ni * 16;
                if ((!edge || col < TS) && d >= thr && col != amc) {
                    int slot = atomicAdd(&cnt[row], 1);
                    if (slot < CAP) {
                        uint2 pr; pr.x = (unsigned)col; pr.y = __float_as_uint(d);
                        cand[row][slot] = pr;
                    }
                }
            }
        }
    }
    __syncthreads();

    // ---- write record (coalesced: consecutive tid -> consecutive rows) ----
    if (tid < 128) {
        ull k = key[tid];
        float mx = funsort((unsigned)(k >> 32));
        int amc = 8191 - (int)(k & 0xFFFFFFFFull);
        int cn = min(cnt[tid], CAP);
        size_t rowg = (size_t)n * QPAD + (size_t)bx * 128 + tid;
        size_t rec = (size_t)by * NROWS + rowg;
        hdr[rec] = make_float2(mx, __int_as_float(cn));
        uint2 a0; a0.x = (unsigned)amc; a0.y = __float_as_uint(mx);
        cpair[rec * CAP] = a0;
        for (int i = 1; i < cn; i++) cpair[rec * CAP + i] = cand[tid][i];
    }
}

// ---------- kernel 4: merge tile records + exact recheck + head, one wave/query ----------

__global__ __launch_bounds__(256) void merge_head(const float2* __restrict__ hdr,
                                                  const uint2* __restrict__ cpair,
                                                  const float* __restrict__ Q,
                                                  const float* __restrict__ S,
                                                  const float* __restrict__ rq,
                                                  const float* __restrict__ rs,
                                                  const float* __restrict__ cls,
                                                  const float* __restrict__ W,
                                                  const float* __restrict__ bb,
                                                  float* __restrict__ out) {
    int w = threadIdx.x >> 6, lane = threadIdx.x & 63;
    int qi = blockIdx.x * 4 + w;                   // 5476*4 = 21904 exactly
    int n = qi / TQ, qr = qi - n * TQ;
    size_t rowg = (size_t)n * QPAD + qr;

    // lane l holds tile l's record header (l < RBS)
    float mx_l = -1e30f; int cnt_l = 0;
    if (lane < RBS) {
        float2 h = hdr[(size_t)lane * NROWS + rowg];
        mx_l = h.x; cnt_l = __float_as_int(h.y);
    }
    float gm = mx_l;
    #pragma unroll
    for (int m = 32; m >= 1; m >>= 1) gm = fmaxf(gm, __shfl_xor(gm, m));
    float thr = gm - EPS_SEL;

    const float* qrow = Q + (size_t)qi * DD;
    float4 q4[3];
    #pragma unroll
    for (int i = 0; i < 3; i++) q4[i] = ((const float4*)qrow)[lane + i * 64];
    float rqv = rq[qi];

    float bestd = -1e30f; int bidx = 0x7FFFFFFF;

    auto recheck = [&](int sidx) {
        const float* srow = S + ((size_t)n * TS + sidx) * DD;
        float part = 0.f;
        #pragma unroll
        for (int k = 0; k < 3; k++) {
            float4 s4 = ((const float4*)srow)[lane + k * 64];
            part += q4[k].x * s4.x + q4[k].y * s4.y + q4[k].z * s4.z + q4[k].w * s4.w;
        }
        part = waveReduceSum(part);                 // bit-identical on all lanes
        float dot = part * rqv * rs[(size_t)n * TS + sidx];
        if (dot > bestd || (dot == bestd && sidx < bidx)) { bestd = dot; bidx = sidx; }
    };

    // only tiles whose max is within EPS of gm can hold candidates; usually 1-2
    ull ball = __ballot(lane < RBS && mx_l >= thr);
    while (ball) {
        int src = __ffsll((long long)ball) - 1;
        ball &= ball - 1;
        int cn = __shfl(cnt_l, src);
        size_t rec = (size_t)src * NROWS + rowg;
        for (int i = 0; i < cn; i++) {
            uint2 pr = cpair[rec * CAP + i];        // wave-uniform -> broadcast load
            float ad = __uint_as_float(pr.y);
            if (ad >= thr) recheck((int)pr.x);      // exact fp32 verify
        }
    }
    if (bidx == 0x7FFFFFFF) bidx = 0;               // unreachable guard (gm rec slot 0)
    float dmin = 1.0f - bestd;

    // head: sigmoid(q_n·W0 + s_n·W1 + cls·W2 + b)
    const float* srow = S + ((size_t)n * TS + bidx) * DD;
    const float* clsr = cls + (size_t)n * DD;
    float rsv = rs[(size_t)n * TS + bidx];
    float aq = 0.f, as_ = 0.f, ac = 0.f;
    #pragma unroll
    for (int i = 0; i < 3; i++) {
        float4 s4 = ((const float4*)srow)[lane + i * 64];
        float4 c4 = ((const float4*)clsr)[lane + i * 64];
        float4 w0 = ((const float4*)W)[lane + i * 64];
        float4 w1 = ((const float4*)(W + DD))[lane + i * 64];
        float4 w2 = ((const float4*)(W + 2 * DD))[lane + i * 64];
        aq += q4[i].x * w0.x + q4[i].y * w0.y + q4[i].z * w0.z + q4[i].w * w0.w;
        as_ += s4.x * w1.x + s4.y * w1.y + s4.z * w1.z + s4.w * w1.w;
        ac += c4.x * w2.x + c4.y * w2.y + c4.z * w2.z + c4.w * w2.w;
    }
    float tot = waveReduceSum(aq * rqv + as_ * rsv + ac);
    if (lane == 0) {
        float logit = tot + bb[0];
        float pred = 1.0f / (1.0f + expf(-logit));
        out[qi] = pred * dmin;
        out[NB * TQ + qi] = pred;
    }
}

// ---------- launch ----------

extern "C" void kernel_launch(void* const* d_in, const int* in_sizes, int n_in,
                              void* d_out, int out_size, void* d_ws, size_t ws_size,
                              hipStream_t stream) {
    const float* Q  = (const float*)d_in[0];
    const float* S  = (const float*)d_in[1];
    const float* XC = (const float*)d_in[2];
    const float* W  = (const float*)d_in[3];
    const float* B  = (const float*)d_in[4];
    (void)in_sizes; (void)n_in; (void)out_size;

    char* ws = (char*)d_ws;
    ushort* Qh    = (ushort*)ws;                          //  34,603,008 B
    ushort* Sh    = (ushort*)(ws + 34603008ull);          // 135,266,304 B -> 169,869,312
    float*  rq    = (float*)(ws + 169869312ull);          //      87,616 B -> 169,956,928
    float*  rs    = (float*)(ws + 169956928ull);          //     350,464 B -> 170,307,392
    float*  cls   = (float*)(ws + 170307392ull);          //      49,152 B -> 170,356,544
    float2* hdr   = (float2*)(ws + 170356544ull);         //   7,749,632 B -> 178,106,176
    uint2*  cpair = (uint2*)(ws + 178106176ull);          //  61,997,056 B -> 240,103,232
    // total 240,103,232 B (ws proven >= 417 MB previously)
    if (ws_size < 240103232ull) return;

    cls_kernel<<<NB, 256, 0, stream>>>(XC, cls);

    // norms: (16*1369 + 16*5476) waves = 109,520 / 4 per block = 27,380 blocks
    norm_kernel<<<27380, 256, 0, stream>>>(Q, S, rq, rs);

    // pack: one block per (kb, row-block, n)
    dim3 pgrid(KB, RBQ + RBS, NB);                        // (24, 54, 16) = 20,736 blocks
    pack_kernel<<<pgrid, 256, 0, stream>>>(Q, S, rq, rs, Qh, Sh);

    dim3 grid(RBQ, RBS, NB);                              // (11, 43, 16) = 7568 blocks
    gemm_sel<<<grid, 256, 0, stream>>>(Qh, Sh, hdr, cpair);

    merge_head<<<(NB * TQ) / 4, 256, 0, stream>>>(hdr, cpair, Q, S, rq, rs,
                                                  cls, W, B, (float*)d_out);
}